// Round 2
// baseline (258.462 us; speedup 1.0000x reference)
//
#include <hip/hip_runtime.h>
#include <hip/hip_cooperative_groups.h>
#include <math.h>

namespace cg = cooperative_groups;

#define HIDDEN 1000
#define K4 250   // HIDDEN/4 float4s per row

__device__ __forceinline__ float sigmoidf_(float x) {
  return 1.f / (1.f + expf(-x));
}

// Single wave-level dot of 1000 floats (w row vs v), result broadcast to all lanes.
__device__ __forceinline__ float wave_dot1(const float4* __restrict__ w,
                                           const float4* __restrict__ v,
                                           int lane) {
  float a = 0.f;
  for (int c = lane; c < K4; c += 64) {
    float4 x = w[c], y = v[c];
    a = fmaf(x.x, y.x, a); a = fmaf(x.y, y.y, a);
    a = fmaf(x.z, y.z, a); a = fmaf(x.w, y.w, a);
  }
  #pragma unroll
  for (int off = 32; off; off >>= 1) a += __shfl_xor(a, off);
  return a;
}

// Dual wave-level dot: (w1·v1, w2·v2) with interleaved loads for deep MLP.
__device__ __forceinline__ void wave_dot2(const float4* __restrict__ w1,
                                          const float4* __restrict__ v1,
                                          const float4* __restrict__ w2,
                                          const float4* __restrict__ v2,
                                          int lane, float& d1, float& d2) {
  float a1 = 0.f, a2 = 0.f;
  for (int c = lane; c < K4; c += 64) {
    float4 x1 = w1[c], y1 = v1[c];
    float4 x2 = w2[c], y2 = v2[c];
    a1 = fmaf(x1.x, y1.x, a1); a1 = fmaf(x1.y, y1.y, a1);
    a1 = fmaf(x1.z, y1.z, a1); a1 = fmaf(x1.w, y1.w, a1);
    a2 = fmaf(x2.x, y2.x, a2); a2 = fmaf(x2.y, y2.y, a2);
    a2 = fmaf(x2.z, y2.z, a2); a2 = fmaf(x2.w, y2.w, a2);
  }
  #pragma unroll
  for (int off = 32; off; off >>= 1) {
    a1 += __shfl_xor(a1, off);
    a2 += __shfl_xor(a2, off);
  }
  d1 = a1; d2 = a2;
}

// One fused cooperative kernel:
//   250 blocks x 768 threads (12 waves). Block b owns neurons j = 4b..4b+3.
//   Wave w (0..11): local neuron nidx = w/3, gate g = w%3 (0:r, 1:z, 2:n).
//   Stage 0: gh0 row dot + tiny gi0 + gate -> h0.
//   Stage l (1..7): dual dot (gi_l row with h_{l-1}, gh_l row with hiddens[l]),
//                   LDS combine, gate -> h_l.  grid.sync() between stages.
//   Tail: block 0 computes flow = W_out . h7 + b_out.
__global__ __launch_bounds__(768, 3)
void gru_fused(const float* __restrict__ x,        // [2]
               const float* __restrict__ hiddens,  // [8*1000]
               const float* __restrict__ Wih0,     // [3000*2]
               const float* __restrict__ Wih,      // [7*3000*1000]
               const float* __restrict__ Whh,      // [8*3000*1000]
               const float* __restrict__ bih,      // [8*3000]
               const float* __restrict__ bhh,      // [8*3000]
               const float* __restrict__ Wout,     // [1000]
               const float* __restrict__ bout,     // [1]
               float* __restrict__ h_buf,          // ws [8*1000]
               float* __restrict__ out)            // [8001]
{
  const int tid  = threadIdx.x;
  const int wave = tid >> 6;       // 0..11
  const int lane = tid & 63;
  const int nidx = wave / 3;       // 0..3 local neuron
  const int g    = wave % 3;       // gate row group
  const int j    = blockIdx.x * 4 + nidx;   // neuron 0..999

  __shared__ float s_gi[4][3];
  __shared__ float s_gh[4][3];
  __shared__ float sred[12];

  cg::grid_group grid = cg::this_grid();

  // ---------------- stage 0 ----------------
  {
    const float4* wrow = reinterpret_cast<const float4*>(
        Whh + (size_t)(g * 1000 + j) * HIDDEN);
    const float4* h0 = reinterpret_cast<const float4*>(hiddens);
    float gh = wave_dot1(wrow, h0, lane);
    if (lane == 0) s_gh[nidx][g] = gh + bhh[g * 1000 + j];
    __syncthreads();
    if (tid < 4) {
      const int jj = blockIdx.x * 4 + tid;
      const float x0 = x[0], x1v = x[1];
      float gir = fmaf(Wih0[2*jj],          x0, Wih0[2*jj+1]          * x1v) + bih[jj];
      float giz = fmaf(Wih0[2*(1000+jj)],   x0, Wih0[2*(1000+jj)+1]   * x1v) + bih[1000+jj];
      float gin = fmaf(Wih0[2*(2000+jj)],   x0, Wih0[2*(2000+jj)+1]   * x1v) + bih[2000+jj];
      float r = sigmoidf_(gir + s_gh[tid][0]);
      float z = sigmoidf_(giz + s_gh[tid][1]);
      float n = tanhf(gin + r * s_gh[tid][2]);
      float h = (1.f - z) * n + z * hiddens[jj];
      h_buf[jj] = h;
      out[1 + jj] = h;
    }
  }

  // ---------------- stages 1..7 ----------------
  for (int l = 1; l < 8; ++l) {
    grid.sync();
    const float4* hin   = reinterpret_cast<const float4*>(h_buf   + (size_t)(l - 1) * HIDDEN);
    const float4* hprev = reinterpret_cast<const float4*>(hiddens + (size_t)l * HIDDEN);
    const float4* wgi = reinterpret_cast<const float4*>(
        Wih + ((size_t)(l - 1) * 3000 + g * 1000 + j) * HIDDEN);
    const float4* wgh = reinterpret_cast<const float4*>(
        Whh + ((size_t)l * 3000 + g * 1000 + j) * HIDDEN);

    float gi, gh;
    wave_dot2(wgi, hin, wgh, hprev, lane, gi, gh);
    if (lane == 0) {
      s_gi[nidx][g] = gi + bih[l * 3000 + g * 1000 + j];
      s_gh[nidx][g] = gh + bhh[l * 3000 + g * 1000 + j];
    }
    __syncthreads();
    if (tid < 4) {
      const int jj = blockIdx.x * 4 + tid;
      float r = sigmoidf_(s_gi[tid][0] + s_gh[tid][0]);
      float z = sigmoidf_(s_gi[tid][1] + s_gh[tid][1]);
      float n = tanhf(s_gi[tid][2] + r * s_gh[tid][2]);
      float h = (1.f - z) * n + z * hiddens[(size_t)l * HIDDEN + jj];
      h_buf[l * HIDDEN + jj] = h;
      out[1 + l * HIDDEN + jj] = h;
    }
    __syncthreads();
  }

  // ---------------- flow ----------------
  grid.sync();
  if (blockIdx.x == 0) {
    const float* h7 = h_buf + 7 * HIDDEN;
    float acc = 0.f;
    for (int i = tid; i < HIDDEN; i += 768) acc += Wout[i] * h7[i];
    #pragma unroll
    for (int off = 32; off; off >>= 1) acc += __shfl_xor(acc, off);
    if (lane == 0) sred[wave] = acc;
    __syncthreads();
    if (tid == 0) {
      float s = 0.f;
      #pragma unroll
      for (int i = 0; i < 12; ++i) s += sred[i];
      out[0] = s + bout[0];
    }
  }
}

extern "C" void kernel_launch(void* const* d_in, const int* in_sizes, int n_in,
                              void* d_out, int out_size, void* d_ws, size_t ws_size,
                              hipStream_t stream) {
  const float* x       = (const float*)d_in[0];
  const float* hiddens = (const float*)d_in[1];
  const float* Wih0    = (const float*)d_in[2];
  const float* Wih     = (const float*)d_in[3];
  const float* Whh     = (const float*)d_in[4];
  const float* bih     = (const float*)d_in[5];
  const float* bhh     = (const float*)d_in[6];
  const float* Wout    = (const float*)d_in[7];
  const float* bout    = (const float*)d_in[8];
  float* h_buf = (float*)d_ws;        // 8000 floats
  float* out   = (float*)d_out;       // 8001 floats

  void* args[] = {(void*)&x, (void*)&hiddens, (void*)&Wih0, (void*)&Wih,
                  (void*)&Whh, (void*)&bih, (void*)&bhh, (void*)&Wout,
                  (void*)&bout, (void*)&h_buf, (void*)&out};
  hipLaunchCooperativeKernel((void*)gru_fused, dim3(250), dim3(768),
                             args, 0, stream);
}

// Round 3
// 59.045 us; speedup vs baseline: 4.3773x; 4.3773x over previous
//
#include <hip/hip_runtime.h>
#include <math.h>

#define HIDDEN 1000
#define K4 250   // HIDDEN / 4 float4s per row

__device__ __forceinline__ float sigmoidf_(float x) {
  return 1.f / (1.f + expf(-x));
}

// Wave-level dot product of two 1000-float vectors (both 16B aligned).
// Returns full sum in ALL lanes (butterfly reduce).
__device__ __forceinline__ float wave_dot1000(const float* __restrict__ w,
                                              const float* __restrict__ v,
                                              int lane) {
  const float4* w4 = reinterpret_cast<const float4*>(w);
  const float4* v4 = reinterpret_cast<const float4*>(v);
  float acc = 0.f;
  for (int c = lane; c < K4; c += 64) {
    float4 a = w4[c];
    float4 b = v4[c];
    acc = fmaf(a.x, b.x, acc);
    acc = fmaf(a.y, b.y, acc);
    acc = fmaf(a.z, b.z, acc);
    acc = fmaf(a.w, b.w, acc);
  }
  #pragma unroll
  for (int off = 32; off; off >>= 1) acc += __shfl_xor(acc, off);
  return acc;
}

// Phase A: all W_hh matvecs (parallel across layers) + fused layer-0 cell.
// Blocks [0,250): layer-0 neurons (wave per neuron j: 3 gh dots + tiny gi + gate).
// Blocks [250,5500): gh rows for layers 1..7 (wave per row), +bhh, -> gh_ws.
__global__ void gru_phaseA(const float* __restrict__ x,        // [2]
                           const float* __restrict__ hiddens,  // [8*1000]
                           const float* __restrict__ Wih0,     // [3000*2]
                           const float* __restrict__ Whh,      // [8*3000*1000]
                           const float* __restrict__ bih,      // [8*3000]
                           const float* __restrict__ bhh,      // [8*3000]
                           float* __restrict__ gh_ws,          // [7*3000]
                           float* __restrict__ h_buf,          // [8*1000]
                           float* __restrict__ out)            // [8001]
{
  const int wave = threadIdx.x >> 6;
  const int lane = threadIdx.x & 63;
  const int b = blockIdx.x;

  if (b < 250) {
    const int j = b * 4 + wave;            // neuron 0..999
    const float* h0 = hiddens;             // layer 0 prev hidden
    float ghr = wave_dot1000(Whh + (size_t)(j)        * HIDDEN, h0, lane) + bhh[j];
    float ghz = wave_dot1000(Whh + (size_t)(1000 + j) * HIDDEN, h0, lane) + bhh[1000 + j];
    float ghn = wave_dot1000(Whh + (size_t)(2000 + j) * HIDDEN, h0, lane) + bhh[2000 + j];
    if (lane == 0) {
      const float x0 = x[0], x1 = x[1];
      float gir = Wih0[2*j]        * x0 + Wih0[2*j+1]        * x1 + bih[j];
      float giz = Wih0[2*(1000+j)] * x0 + Wih0[2*(1000+j)+1] * x1 + bih[1000 + j];
      float gin = Wih0[2*(2000+j)] * x0 + Wih0[2*(2000+j)+1] * x1 + bih[2000 + j];
      float r = sigmoidf_(gir + ghr);
      float z = sigmoidf_(giz + ghz);
      float n = tanhf(gin + r * ghn);
      float h = (1.f - z) * n + z * h0[j];
      h_buf[j] = h;
      out[1 + j] = h;
    }
  } else {
    const int rg = (b - 250) * 4 + wave;   // 0..20999
    const int l = rg / 3000 + 1;           // layer 1..7
    const int r = rg % 3000;               // row within layer
    const float* hl = hiddens + (size_t)l * HIDDEN;
    float gh = wave_dot1000(Whh + ((size_t)l * 3000 + r) * HIDDEN, hl, lane)
             + bhh[l * 3000 + r];
    if (lane == 0) gh_ws[rg] = gh;
  }
}

// One layer (l in 1..7): block per neuron. Each thread t<250 issues 4
// independent float4 loads (h_in + 3 weight-row segments), one partial FMA
// chain per gate, then wave shuffle + LDS reduce. Thread 0 applies the gate.
__global__ __launch_bounds__(256)
void gru_layer2(const int l,
                const float* __restrict__ hiddens,  // [8*1000]
                const float* __restrict__ Wih,      // [7*3000*1000]
                const float* __restrict__ bih,      // [8*3000]
                const float* __restrict__ gh_ws,    // [7*3000] (bhh included)
                float* __restrict__ h_buf,          // [8*1000]
                float* __restrict__ out)            // [8001]
{
  const int t = threadIdx.x;
  const int j = blockIdx.x;                // neuron 0..999
  const float4* W4  = reinterpret_cast<const float4*>(
      Wih + (size_t)(l - 1) * 3000 * HIDDEN);
  const float4* hin = reinterpret_cast<const float4*>(
      h_buf + (size_t)(l - 1) * HIDDEN);

  float aR = 0.f, aZ = 0.f, aN = 0.f;
  if (t < K4) {
    float4 hv = hin[t];
    float4 wr = W4[(size_t)(j)        * K4 + t];
    float4 wz = W4[(size_t)(1000 + j) * K4 + t];
    float4 wn = W4[(size_t)(2000 + j) * K4 + t];
    aR = fmaf(wr.x, hv.x, fmaf(wr.y, hv.y, fmaf(wr.z, hv.z, wr.w * hv.w)));
    aZ = fmaf(wz.x, hv.x, fmaf(wz.y, hv.y, fmaf(wz.z, hv.z, wz.w * hv.w)));
    aN = fmaf(wn.x, hv.x, fmaf(wn.y, hv.y, fmaf(wn.z, hv.z, wn.w * hv.w)));
  }
  #pragma unroll
  for (int off = 32; off; off >>= 1) {
    aR += __shfl_xor(aR, off);
    aZ += __shfl_xor(aZ, off);
    aN += __shfl_xor(aN, off);
  }
  __shared__ float s[4][3];
  const int wave = t >> 6, lane = t & 63;
  if (lane == 0) { s[wave][0] = aR; s[wave][1] = aZ; s[wave][2] = aN; }
  __syncthreads();
  if (t == 0) {
    float gir = s[0][0] + s[1][0] + s[2][0] + s[3][0] + bih[l*3000 + j];
    float giz = s[0][1] + s[1][1] + s[2][1] + s[3][1] + bih[l*3000 + 1000 + j];
    float gin = s[0][2] + s[1][2] + s[2][2] + s[3][2] + bih[l*3000 + 2000 + j];
    float ghr = gh_ws[(l-1)*3000 + j];
    float ghz = gh_ws[(l-1)*3000 + 1000 + j];
    float ghn = gh_ws[(l-1)*3000 + 2000 + j];
    float r = sigmoidf_(gir + ghr);
    float z = sigmoidf_(giz + ghz);
    float n = tanhf(gin + r * ghn);
    float h = (1.f - z) * n + z * hiddens[(size_t)l * HIDDEN + j];
    h_buf[l * HIDDEN + j] = h;
    out[1 + l * HIDDEN + j] = h;
  }
}

// flow = W_out @ h7 + b_out
__global__ void gru_flow(const float* __restrict__ Wout,   // [1000]
                         const float* __restrict__ bout,   // [1]
                         const float* __restrict__ h_buf,  // [8*1000]
                         float* __restrict__ out)          // [8001]
{
  const int t = threadIdx.x;               // 256 threads
  const float* h7 = h_buf + 7 * HIDDEN;
  float acc = 0.f;
  for (int i = t; i < HIDDEN; i += 256) acc += Wout[i] * h7[i];
  #pragma unroll
  for (int off = 32; off; off >>= 1) acc += __shfl_xor(acc, off);
  __shared__ float s[4];
  const int wave = t >> 6, lane = t & 63;
  if (lane == 0) s[wave] = acc;
  __syncthreads();
  if (t == 0) out[0] = s[0] + s[1] + s[2] + s[3] + bout[0];
}

extern "C" void kernel_launch(void* const* d_in, const int* in_sizes, int n_in,
                              void* d_out, int out_size, void* d_ws, size_t ws_size,
                              hipStream_t stream) {
  const float* x       = (const float*)d_in[0];
  const float* hiddens = (const float*)d_in[1];
  const float* Wih0    = (const float*)d_in[2];
  const float* Wih     = (const float*)d_in[3];
  const float* Whh     = (const float*)d_in[4];
  const float* bih     = (const float*)d_in[5];
  const float* bhh     = (const float*)d_in[6];
  const float* Wout    = (const float*)d_in[7];
  const float* bout    = (const float*)d_in[8];
  float* out   = (float*)d_out;
  float* gh_ws = (float*)d_ws;          // 21000 floats (layers 1..7 gh)
  float* h_buf = gh_ws + 21000;         // 8000 floats (per-layer h, 16B-aligned)

  gru_phaseA<<<5500, 256, 0, stream>>>(x, hiddens, Wih0, Whh, bih, bhh,
                                       gh_ws, h_buf, out);
  for (int l = 1; l < 8; ++l) {
    gru_layer2<<<1000, 256, 0, stream>>>(l, hiddens, Wih, bih, gh_ws, h_buf, out);
  }
  gru_flow<<<1, 256, 0, stream>>>(Wout, bout, h_buf, out);
}